// Round 5
// baseline (125.315 us; speedup 1.0000x reference)
//
#include <hip/hip_runtime.h>
#include <cfloat>
#include <climits>

#define NB 16
#define NC 32
#define NZ 48
#define NY 48
#define YZ 2304             // NY*NZ
#define XYZ 110592          // 48^3
#define SUM_NUM 56623104.0  // 16*32*110592
#define VPT 4               // voxels per thread (one float4, z-aligned)
#define TPB 256
#define VPB (VPT*TPB)       // 1024 voxels per block
#define PBS (XYZ/VPB)       // 108 blocks per sample
#define GRID (NB*PBS)       // 1728

struct BP {
  float s0[NC], sx[NC], sxx[NC], sy[NC], syy[NC], mx[NC];
  int   mi[NC];
  float A, B, vs;
};
struct Ws { BP bp[GRID]; };

// top-2 update, strict '>' (first occurrence wins)
#define TOP2(m1, m2, x) do { \
    if ((x) > (m1)) { (m2) = (m1); (m1) = (x); } \
    else if ((x) > (m2)) (m2) = (x); \
  } while (0)

__global__ __launch_bounds__(256, 2) void k_fused(const float* __restrict__ f,
                                                  Ws* __restrict__ ws) {
  const int bb = blockIdx.x / PBS;
  const int pb = blockIdx.x - bb * PBS;
  const int t  = threadIdx.x;
  const int g  = pb * VPB + t * VPT;       // voxel base within sample
  const float* __restrict__ p = f + (size_t)bb * NC * XYZ + g;

  // per-channel state: s0 only (x,y thread-constant) + max value + packed arg-j
  float s0c[NC], mvc[NC];
  unsigned jlo = 0u, jhi = 0u;
  // per-voxel (component) state for the exclude-self top-2
  float m1x=-FLT_MAX, m1y=-FLT_MAX, m1z=-FLT_MAX, m1w=-FLT_MAX;
  float m2x=-FLT_MAX, m2y=-FLT_MAX, m2z=-FLT_MAX, m2w=-FLT_MAX;
  float qsx=0.f, qsy=0.f, qsz=0.f, qsw=0.f;   // per-component sq sums over channels
  float vsum = 0.f;

#pragma unroll
  for (int c = 0; c < NC; ++c) {
    const float4 v = *reinterpret_cast<const float4*>(p + (size_t)c * XYZ);
    const float qx = v.x*v.x, qy = v.y*v.y, qz = v.z*v.z, qw = v.w*v.w;
    qsx += qx; qsy += qy; qsz += qz; qsw += qw;
    vsum += (v.x + v.y) + (v.z + v.w);
    s0c[c] = (qx + qy) + (qz + qw);
    float m = v.x; int j = 0;                 // strict '>' keeps first index
    if (v.y > m) { m = v.y; j = 1; }
    if (v.z > m) { m = v.z; j = 2; }
    if (v.w > m) { m = v.w; j = 3; }
    mvc[c] = m;
    if (c < 16) jlo |= (unsigned)j << (2*c); else jhi |= (unsigned)j << (2*(c-16));
    TOP2(m1x, m2x, v.x);
    TOP2(m1y, m2y, v.y);
    TOP2(m1z, m2z, v.z);
    TOP2(m1w, m2w, v.w);
  }

  // per-voxel div moments: A = sum sq*mo^2, B = sum sq*mo (top-2 trick)
  float A = 0.f, Bv = 0.f;
  {
    float q, r;
    q = m1x*m1x; r = qsx - q; A += q*r + m2x*m2x*q; Bv += m1x*r + m2x*q;
    q = m1y*m1y; r = qsy - q; A += q*r + m2y*m2y*q; Bv += m1y*r + m2y*q;
    q = m1z*m1z; r = qsz - q; A += q*r + m2z*m2z*q; Bv += m1z*r + m2z*q;
    q = m1w*m1w; r = qsw - q; A += q*r + m2w*m2w*q; Bv += m1w*r + m2w*q;
  }

  // ---------------- block epilogue: LDS transpose-reduce ----------------
  __shared__ float sb[TPB][NC+1];     // 33.8 KB (pad 33 -> conflict-free)
  __shared__ float xyr[TPB][2];       // writer (x,y) table
  __shared__ float pc5[8][NC][5];
  __shared__ float pcv[8][NC];
  __shared__ int   pct[8][NC];
  __shared__ int   wint[NC];
  __shared__ float rr[4][3];

  const int xi = g / YZ;
  const int yi = (g / NZ) % NY;       // thread's 4 voxels share (x,y)
  xyr[t][0] = (float)xi; xyr[t][1] = (float)yi;
#pragma unroll
  for (int c = 0; c < NC; ++c) sb[t][c] = s0c[c];
  __syncthreads();

  const int cc = t & 31, ch = t >> 5;           // channel, row-chunk
  {
    float a0=0.f, a1=0.f, a2=0.f, a3=0.f, a4=0.f;
    for (int j = 0; j < 32; ++j) {
      const int row = (ch << 5) + j;
      const float s  = sb[row][cc];
      const float xw = xyr[row][0], yw = xyr[row][1];
      a0 += s;
      a1 = fmaf(s, xw, a1);  a2 = fmaf(s, xw*xw, a2);
      a3 = fmaf(s, yw, a3);  a4 = fmaf(s, yw*yw, a4);
    }
    pc5[ch][cc][0]=a0; pc5[ch][cc][1]=a1; pc5[ch][cc][2]=a2;
    pc5[ch][cc][3]=a3; pc5[ch][cc][4]=a4;
  }
  __syncthreads();

  BP* bp = &ws->bp[blockIdx.x];
  if (t < NC) {
    float b0=0.f,b1=0.f,b2=0.f,b3=0.f,b4=0.f;
    for (int k = 0; k < 8; ++k) {
      b0+=pc5[k][t][0]; b1+=pc5[k][t][1]; b2+=pc5[k][t][2];
      b3+=pc5[k][t][3]; b4+=pc5[k][t][4];
    }
    bp->s0[t]=b0; bp->sx[t]=b1; bp->sxx[t]=b2; bp->sy[t]=b3; bp->syy[t]=b4;
  }
  __syncthreads();                     // sb consumers done -> reuse for max

#pragma unroll
  for (int c = 0; c < NC; ++c) sb[t][c] = mvc[c];
  __syncthreads();
  {
    float bm = -FLT_MAX; int bt = 0;
    for (int j = 0; j < 32; ++j) {     // ascending row = ascending voxel idx
      const int row = (ch << 5) + j;
      const float v2 = sb[row][cc];
      if (v2 > bm) { bm = v2; bt = row; }
    }
    pcv[ch][cc] = bm; pct[ch][cc] = bt;
  }
  __syncthreads();
  if (t < NC) {
    float bm = -FLT_MAX; int bt = 0;
    for (int k = 0; k < 8; ++k) {      // ascending chunk keeps first on ties
      const float v2 = pcv[k][t];
      if (v2 > bm) { bm = v2; bt = pct[k][t]; }
    }
    bp->mx[t] = bm; wint[t] = bt;
  }
  __syncthreads();                     // max scan done -> reuse sb as ints
  {
    int* si = reinterpret_cast<int*>(&sb[0][0]);
#pragma unroll
    for (int c = 0; c < NC; ++c) {
      const int j = (c < 16) ? (int)((jlo >> (2*c)) & 3u)
                             : (int)((jhi >> (2*(c-16))) & 3u);
      si[t*(NC+1) + c] = j;
    }
  }
  __syncthreads();
  if (t < NC) {
    const int wt = wint[t];
    const int j  = reinterpret_cast<int*>(&sb[0][0])[wt*(NC+1) + t];
    bp->mi[t] = pb * VPB + wt * VPT + j;   // sample-local voxel index
  }

  // block reduce A, B, vsum
  for (int off = 32; off > 0; off >>= 1) {
    A    += __shfl_down(A,    off);
    Bv   += __shfl_down(Bv,   off);
    vsum += __shfl_down(vsum, off);
  }
  const int w = t >> 6, l = t & 63;
  if (l == 0) { rr[w][0] = A; rr[w][1] = Bv; rr[w][2] = vsum; }
  __syncthreads();
  if (t == 0) {
    bp->A  = (rr[0][0]+rr[1][0]) + (rr[2][0]+rr[3][0]);
    bp->B  = (rr[0][1]+rr[1][1]) + (rr[2][1]+rr[3][1]);
    bp->vs = (rr[0][2]+rr[1][2]) + (rr[2][2]+rr[3][2]);
  }
}

// ---- finalize: thread = (b,c); merge 108 block partials; assemble in f64 ----
__global__ __launch_bounds__(512) void k_fin(const Ws* __restrict__ ws,
                                             float* __restrict__ out) {
  const int t = threadIdx.x;
  const int b = t >> 5, c = t & 31;
  double s0=0, sx=0, sxx=0, sy=0, syy=0;
  float mv = -FLT_MAX; int mi = INT_MAX;
  for (int k = 0; k < PBS; ++k) {
    const BP* p = &ws->bp[b*PBS + k];
    s0 += p->s0[c]; sx += p->sx[c]; sxx += p->sxx[c];
    sy += p->sy[c]; syy += p->syy[c];
    const float ov = p->mx[c]; const int oi = p->mi[c];
    if (ov > mv || (ov == mv && oi < mi)) { mv = ov; mi = oi; }
  }
  const double mx = (double)(mi / YZ);
  const double my = (double)((mi / NZ) % NY);
  const double mz = (double)(mi % NZ);
  double dis = (mx*mx + my*my)*s0 - 2.0*mx*sx - 2.0*my*sy + sxx + syy
             + 2304.0*(48.0*mz*mz - 2256.0*mz + 35720.0);
  double s0t = s0, a = 0.0, bb2 = 0.0, vsum = 0.0;
  for (int i = t; i < GRID; i += 512) {
    a += ws->bp[i].A; bb2 += ws->bp[i].B; vsum += ws->bp[i].vs;
  }

  for (int off = 32; off > 0; off >>= 1) {
    dis  += __shfl_down(dis,  off);
    s0t  += __shfl_down(s0t,  off);
    a    += __shfl_down(a,    off);
    bb2  += __shfl_down(bb2,  off);
    vsum += __shfl_down(vsum, off);
  }
  __shared__ double sd[8][5];
  const int wid = t >> 6;
  if ((t & 63) == 0) { sd[wid][0]=dis; sd[wid][1]=s0t; sd[wid][2]=a; sd[wid][3]=bb2; sd[wid][4]=vsum; }
  __syncthreads();
  if (t == 0) {
    for (int q = 1; q < 8; ++q) {
      dis += sd[q][0]; s0t += sd[q][1]; a += sd[q][2]; bb2 += sd[q][3]; vsum += sd[q][4];
    }
    const double mgr = vsum / SUM_NUM;
    out[0] = (float)(dis / SUM_NUM);
    out[1] = (float)((a - 2.0*mgr*bb2 + mgr*mgr*s0t) / SUM_NUM);
  }
}

extern "C" void kernel_launch(void* const* d_in, const int* in_sizes, int n_in,
                              void* d_out, int out_size, void* d_ws, size_t ws_size,
                              hipStream_t stream) {
  const float* f = (const float*)d_in[0];
  Ws* ws = (Ws*)d_ws;
  float* out = (float*)d_out;
  hipLaunchKernelGGL(k_fused, dim3(GRID), dim3(TPB), 0, stream, f, ws);
  hipLaunchKernelGGL(k_fin,   dim3(1),    dim3(512), 0, stream, ws, out);
}